// Round 7
// baseline (356.855 us; speedup 1.0000x reference)
//
#include <hip/hip_runtime.h>

typedef _Float16 f16;
typedef _Float16 f16x4 __attribute__((ext_vector_type(4)));
typedef _Float16 f16x8 __attribute__((ext_vector_type(8)));
typedef float f32x4  __attribute__((ext_vector_type(4)));

#define MFMAH(a, b, c) __builtin_amdgcn_mfma_f32_16x16x32_f16(a, b, c, 0, 0, 0)

constexpr int D = 256;
constexpr int S = 4096;
constexpr int BATCH = 4;
constexpr int NROWS = BATCH * S;           // 16384
constexpr float SCALE = 0.0625f;           // 1/sqrt(256)
constexpr float LOG2E = 1.44269504088896f;
constexpr size_t NE = (size_t)NROWS * D;   // 4.19M elems

// async global->LDS: per-lane src addr, wave-uniform LDS base (+lane*16 by HW)
__device__ __forceinline__ void gll16(const void* g, void* l) {
  __builtin_amdgcn_global_load_lds(
      (const __attribute__((address_space(1))) unsigned int*)g,
      (__attribute__((address_space(3))) unsigned int*)l, 16, 0, 0);
}

// ---------------------------------------------------------------------------
// Prep: Wt[m][n][k] = w_m[k][n] fp16. Write-coalesced (reads L1-absorbed).
// ---------------------------------------------------------------------------
__global__ __launch_bounds__(256)
void prep_wt_kernel(const float* __restrict__ wq, const float* __restrict__ wk,
                    const float* __restrict__ wv, const float* __restrict__ wo,
                    f16* __restrict__ Wt)
{
  const int m = blockIdx.y;
  const float* w = (m == 0) ? wq : (m == 1) ? wk : (m == 2) ? wv : wo;
  int id = blockIdx.x * 256 + threadIdx.x;    // 0..65535
  int n = id >> 8, k = id & 255;
  Wt[((size_t)m << 16) + n * 256 + k] = (f16)w[k * 256 + n];
}

// ---------------------------------------------------------------------------
// QKV projection via MFMA, LDS-transposed coalesced epilogues.
// Q: row-major fp16, scaled by SCALE*LOG2E (base-2 softmax downstream).
// Kf frag(g=key>>4, kc) 1KB: idx = ((ct&1)*2+(l15>>3))*128 + key16*8 + (l15&7)
// Vf frag(gv=key>>5, ct) 1KB: idx = quad*128 + l15*8 + t*4 + r  (perm-packed)
// Layouts identical to round-6 (validated); only the write path changes.
// ---------------------------------------------------------------------------
__global__ __launch_bounds__(256)
void qkv_mfma_kernel(const float* __restrict__ in, const f16* __restrict__ Wt,
                     const float* __restrict__ bq, const float* __restrict__ bk,
                     const float* __restrict__ bv,
                     f16* __restrict__ Qh, f16* __restrict__ Kf, f16* __restrict__ Vf)
{
  __shared__ __align__(16) char smem[32768];
  const int m = blockIdx.y;
  const int tid = threadIdx.x, lane = tid & 63, w = tid >> 6;
  const int l15 = lane & 15, quad = lane >> 4;
  const int row0 = blockIdx.x * 64 + w * 16;
  const f16* Wm = Wt + ((size_t)m << 16);
  const float* bias = (m == 0) ? bq : (m == 1) ? bk : bv;

  f32x4 acc[16];
#pragma unroll
  for (int ct = 0; ct < 16; ++ct) acc[ct] = (f32x4){0.f, 0.f, 0.f, 0.f};

  const float* arow = in + (size_t)(row0 + l15) * 768 + m * 256 + quad * 8;
#pragma unroll
  for (int kc = 0; kc < 8; ++kc) {
    float4 a0 = *(const float4*)(arow + kc * 32);
    float4 a1 = *(const float4*)(arow + kc * 32 + 4);
    f16x8 a;
    a[0] = (f16)a0.x; a[1] = (f16)a0.y; a[2] = (f16)a0.z; a[3] = (f16)a0.w;
    a[4] = (f16)a1.x; a[5] = (f16)a1.y; a[6] = (f16)a1.z; a[7] = (f16)a1.w;
#pragma unroll
    for (int ct = 0; ct < 16; ++ct) {
      f16x8 b = *(const f16x8*)(Wm + (ct * 16 + l15) * 256 + kc * 32 + quad * 8);
      acc[ct] = MFMAH(a, b, acc[ct]);
    }
  }

  const int b_ = row0 >> 12;

  if (m == 0) {
    // ---- Q: wave-local 8KB region, row-major, then coalesced dump
    f16* ws = (f16*)(smem + w * 8192);
    const float sc = SCALE * LOG2E;
#pragma unroll
    for (int ct = 0; ct < 16; ++ct) {
      float bct = bias[ct * 16 + l15];
#pragma unroll
      for (int r = 0; r < 4; ++r)
        ws[(quad * 4 + r) * 256 + ct * 16 + l15] = (f16)((acc[ct][r] + bct) * sc);
    }
    f16* dst = Qh + (size_t)row0 * 256;
#pragma unroll
    for (int i = 0; i < 8; ++i)
      *(uint4*)(dst + lane * 8 + i * 512) = *(const uint4*)(ws + lane * 8 + i * 512);
  } else if (m == 1) {
    // ---- K: wave-local 8KB region in frag layout, then coalesced dump
    f16* ws = (f16*)(smem + w * 8192);
#pragma unroll
    for (int ct = 0; ct < 16; ++ct) {
      float bct = bias[ct * 16 + l15];
      int base = (ct >> 1) * 512 + ((ct & 1) * 2 + (l15 >> 3)) * 128 + (l15 & 7);
#pragma unroll
      for (int r = 0; r < 4; ++r)
        ws[base + (quad * 4 + r) * 8] = (f16)(acc[ct][r] + bct);
    }
    const int g = (row0 & 4095) >> 4;
    f16* dst = Kf + ((size_t)(b_ * 256 + g)) * 8 * 512;
#pragma unroll
    for (int i = 0; i < 8; ++i)
      *(uint4*)(dst + lane * 8 + i * 512) = *(const uint4*)(ws + lane * 8 + i * 512);
  } else {
    // ---- V: block-level 32KB frag-layout staging (2 gv groups), barrier, dump
    const int t = w & 1;
    f16* ws = (f16*)(smem + (w >> 1) * 16384);
#pragma unroll
    for (int ct = 0; ct < 16; ++ct) {
      float bct = bias[ct * 16 + l15];
      int base = ct * 512 + quad * 128 + l15 * 8 + t * 4;
#pragma unroll
      for (int r = 0; r < 4; ++r)
        ws[base + r] = (f16)(acc[ct][r] + bct);
    }
    __syncthreads();
    const int gv0 = ((blockIdx.x * 64) & 4095) >> 5;
    f16* dst = Vf + ((size_t)(b_ * 128 + gv0)) * 16 * 512;
    const f16* src = (const f16*)smem;
#pragma unroll
    for (int i = 0; i < 8; ++i)
      *(uint4*)(dst + tid * 8 + i * 2048) = *(const uint4*)(src + tid * 8 + i * 2048);
  }
}

// ---------------------------------------------------------------------------
// fp16 MFMA flash attention v7. 512 blocks x 256 thr (4 waves, Tq=32/wave),
// 2 blocks/CU. Split-K=4, 32-key tiles, 32 iters, base-2 softmax.
// Epilogue: LDS-transposed coalesced partial-O store.
// ---------------------------------------------------------------------------
__global__ __launch_bounds__(256, 2)
void attn7_kernel(const f16* __restrict__ Qh, const char* __restrict__ Kf,
                  const char* __restrict__ Vf,
                  f16* __restrict__ Pp, float* __restrict__ Mp, float* __restrict__ Lp)
{
  __shared__ __align__(16) char KVs[2][32768];   // [K 16 frags][V 16 frags]

  const int tid = threadIdx.x, lane = tid & 63, w = tid >> 6;
  const int l15 = lane & 15, quad = lane >> 4;

  const int bx    = blockIdx.x;
  const int combo = bx & 15;
  const int b     = combo & 3;
  const int kz    = combo >> 2;
  const int qb    = bx >> 4;                   // 0..31
  const int qrow0 = qb * 128 + w * 32;
  const int grow  = b * 4096 + qrow0;

  // resident Q B-fragments (n=q=l15, k=quad*8+j per kc)
  f16x8 qf[2][8];
#pragma unroll
  for (int sub = 0; sub < 2; ++sub) {
    const size_t qoff = (size_t)(grow + sub * 16 + l15) * 256 + quad * 8;
#pragma unroll
    for (int kc = 0; kc < 8; ++kc)
      qf[sub][kc] = *(const f16x8*)(Qh + qoff + kc * 32);
  }

  // staging: wave w stages K frags f=4w..4w+3 and V frags f=4w..4w+3
  const char* kg[4];
  const char* vg[4];
#pragma unroll
  for (int i = 0; i < 4; ++i) {
    int f = 4 * w + i;
    kg[i] = Kf + (((size_t)(b * 256 + kz * 64 + (f >> 3))) * 8 + (f & 7)) * 1024
               + lane * 16;
    vg[i] = Vf + (((size_t)(b * 128 + kz * 32)) * 16 + f) * 1024 + lane * 16;
  }
  auto stage = [&](int buf) {
    char* base = &KVs[buf][0];
#pragma unroll
    for (int i = 0; i < 4; ++i) { gll16(kg[i], base + (4 * w + i) * 1024); kg[i] += 16384; }
#pragma unroll
    for (int i = 0; i < 4; ++i) { gll16(vg[i], base + 16384 + (4 * w + i) * 1024); vg[i] += 16384; }
  };

  f32x4 o0[16], o1[16];
#pragma unroll
  for (int ct = 0; ct < 16; ++ct) {
    o0[ct] = (f32x4){0.f, 0.f, 0.f, 0.f};
    o1[ct] = (f32x4){0.f, 0.f, 0.f, 0.f};
  }
  float m0 = -3.0e38f, m1 = -3.0e38f, l0 = 0.f, l1 = 0.f;

  stage(0);

  for (int it = 0; it < 32; ++it) {
    __syncthreads();
    if (it < 31) stage((it + 1) & 1);
    const char* Bf = &KVs[it & 1][0];

    // QK: S^T[key][q] in log2 units (Q pre-scaled by SCALE*log2e)
    f32x4 sA0 = (f32x4){0.f,0.f,0.f,0.f}, sB0 = (f32x4){0.f,0.f,0.f,0.f};
    f32x4 sA1 = (f32x4){0.f,0.f,0.f,0.f}, sB1 = (f32x4){0.f,0.f,0.f,0.f};
#pragma unroll
    for (int kc = 0; kc < 8; ++kc) {
      f16x8 kA = *(const f16x8*)(Bf + kc * 1024 + lane * 16);
      f16x8 kB = *(const f16x8*)(Bf + 8192 + kc * 1024 + lane * 16);
      sA0 = MFMAH(kA, qf[0][kc], sA0);
      sA1 = MFMAH(kA, qf[1][kc], sA1);
      sB0 = MFMAH(kB, qf[0][kc], sB0);
      sB1 = MFMAH(kB, qf[1][kc], sB1);
    }

    // online softmax, base-2 (lane: q=l15; keys quad*4+r per 16-tile)
    float mn0, mn1, al0, al1;
    f16x8 ph0, ph1;
    {
      float t = fmaxf(fmaxf(fmaxf(sA0[0], sA0[1]), fmaxf(sA0[2], sA0[3])),
                      fmaxf(fmaxf(sB0[0], sB0[1]), fmaxf(sB0[2], sB0[3])));
      t = fmaxf(t, __shfl_xor(t, 16));
      t = fmaxf(t, __shfl_xor(t, 32));
      mn0 = fmaxf(m0, t);
      al0 = exp2f(m0 - mn0);
      float ps = 0.f;
#pragma unroll
      for (int r = 0; r < 4; ++r) {
        float pa = exp2f(sA0[r] - mn0);
        float pb = exp2f(sB0[r] - mn0);
        ph0[r] = (f16)pa;  ph0[r + 4] = (f16)pb;
        ps += pa + pb;
      }
      ps += __shfl_xor(ps, 16);
      ps += __shfl_xor(ps, 32);
      l0 = l0 * al0 + ps;
    }
    {
      float t = fmaxf(fmaxf(fmaxf(sA1[0], sA1[1]), fmaxf(sA1[2], sA1[3])),
                      fmaxf(fmaxf(sB1[0], sB1[1]), fmaxf(sB1[2], sB1[3])));
      t = fmaxf(t, __shfl_xor(t, 16));
      t = fmaxf(t, __shfl_xor(t, 32));
      mn1 = fmaxf(m1, t);
      al1 = exp2f(m1 - mn1);
      float ps = 0.f;
#pragma unroll
      for (int r = 0; r < 4; ++r) {
        float pa = exp2f(sA1[r] - mn1);
        float pb = exp2f(sB1[r] - mn1);
        ph1[r] = (f16)pa;  ph1[r + 4] = (f16)pb;
        ps += pa + pb;
      }
      ps += __shfl_xor(ps, 16);
      ps += __shfl_xor(ps, 32);
      l1 = l1 * al1 + ps;
    }

    if (__any(mn0 > m0)) {
      float a0 = __shfl(al0, (quad << 2) + 0);
      float a1 = __shfl(al0, (quad << 2) + 1);
      float a2 = __shfl(al0, (quad << 2) + 2);
      float a3 = __shfl(al0, (quad << 2) + 3);
#pragma unroll
      for (int ct = 0; ct < 16; ++ct) {
        o0[ct][0] *= a0; o0[ct][1] *= a1; o0[ct][2] *= a2; o0[ct][3] *= a3;
      }
    }
    if (__any(mn1 > m1)) {
      float a0 = __shfl(al1, (quad << 2) + 0);
      float a1 = __shfl(al1, (quad << 2) + 1);
      float a2 = __shfl(al1, (quad << 2) + 2);
      float a3 = __shfl(al1, (quad << 2) + 3);
#pragma unroll
      for (int ct = 0; ct < 16; ++ct) {
        o1[ct][0] *= a0; o1[ct][1] *= a1; o1[ct][2] *= a2; o1[ct][3] *= a3;
      }
    }
    m0 = mn0;  m1 = mn1;

    // PV: O += P @ V (perm-packed 32 keys, 1-pass)
#pragma unroll
    for (int ct = 0; ct < 16; ++ct) {
      f16x8 vf = *(const f16x8*)(Bf + 16384 + ct * 1024 + lane * 16);
      o0[ct] = MFMAH(ph0, vf, o0[ct]);
      o1[ct] = MFMAH(ph1, vf, o1[ct]);
    }
  }

  // ---- epilogue: LDS-transposed coalesced partial store (KVs dead; barrier
  // so no wave overwrites buffer 1 while others still read it)
  __syncthreads();
  f16* ws = (f16*)(&KVs[0][0] + w * 16384);    // 32 rows x 256 f16
#pragma unroll
  for (int ct = 0; ct < 16; ++ct) {
#pragma unroll
    for (int r = 0; r < 4; ++r) {
      ws[(quad * 4 + r) * 256 + ct * 16 + l15] = (f16)o0[ct][r];
      ws[(16 + quad * 4 + r) * 256 + ct * 16 + l15] = (f16)o1[ct][r];
    }
  }
  f16* dst = Pp + (size_t)kz * NE + (size_t)grow * 256;
#pragma unroll
  for (int i = 0; i < 16; ++i)
    *(uint4*)(dst + lane * 8 + i * 512) = *(const uint4*)(ws + lane * 8 + i * 512);

  if (lane < 16) {
    Mp[kz * NROWS + grow + l15] = m0;
    Lp[kz * NROWS + grow + l15] = l0;
    Mp[kz * NROWS + grow + 16 + l15] = m1;
    Lp[kz * NROWS + grow + 16 + l15] = l1;
  }
}

// ---------------------------------------------------------------------------
// Fused split-K merge (base-2 weights) + output projection (MFMA).
// ---------------------------------------------------------------------------
__global__ __launch_bounds__(256)
void oproj_mfma_kernel(const f16* __restrict__ Pp, const float* __restrict__ Mp,
                       const float* __restrict__ Lp, const f16* __restrict__ Wto,
                       const float* __restrict__ bo, float* __restrict__ out)
{
  __shared__ f16 xs[64][264];
  const int tid = threadIdx.x, lane = tid & 63, w = tid >> 6;
  const int l15 = lane & 15, quad = lane >> 4;
  const int rb = blockIdx.x * 64;

  const int c4 = (tid & 63) * 4;
  const int rsub = tid >> 6;
#pragma unroll 4
  for (int e = 0; e < 16; ++e) {
    int row = rb + e * 4 + rsub;
    float m[4], l[4];
#pragma unroll
    for (int z = 0; z < 4; ++z) {
      m[z] = Mp[z * NROWS + row];
      l[z] = Lp[z * NROWS + row];
    }
    float mm = fmaxf(fmaxf(m[0], m[1]), fmaxf(m[2], m[3]));
    float wz[4], denom = 0.f;
#pragma unroll
    for (int z = 0; z < 4; ++z) { wz[z] = exp2f(m[z] - mm); denom += wz[z] * l[z]; }
    float inv = 1.0f / denom;
    float s0 = 0.f, s1 = 0.f, s2 = 0.f, s3 = 0.f;
#pragma unroll
    for (int z = 0; z < 4; ++z) {
      f16x4 h = *(const f16x4*)(Pp + (size_t)z * NE + (size_t)row * 256 + c4);
      s0 += wz[z] * (float)h[0];
      s1 += wz[z] * (float)h[1];
      s2 += wz[z] * (float)h[2];
      s3 += wz[z] * (float)h[3];
    }
    f16x4 xv;
    xv[0] = (f16)(s0 * inv); xv[1] = (f16)(s1 * inv);
    xv[2] = (f16)(s2 * inv); xv[3] = (f16)(s3 * inv);
    *(f16x4*)&xs[e * 4 + rsub][c4] = xv;
  }
  __syncthreads();

  f32x4 acc[16];
#pragma unroll
  for (int ct = 0; ct < 16; ++ct) acc[ct] = (f32x4){0.f, 0.f, 0.f, 0.f};
#pragma unroll
  for (int kc = 0; kc < 8; ++kc) {
    f16x8 a = *(const f16x8*)&xs[w * 16 + l15][kc * 32 + quad * 8];
#pragma unroll
    for (int ct = 0; ct < 16; ++ct) {
      f16x8 b = *(const f16x8*)(Wto + (ct * 16 + l15) * 256 + kc * 32 + quad * 8);
      acc[ct] = MFMAH(a, b, acc[ct]);
    }
  }
#pragma unroll
  for (int ct = 0; ct < 16; ++ct) {
    float bct = bo[ct * 16 + l15];
#pragma unroll
    for (int r = 0; r < 4; ++r)
      out[(size_t)(rb + w * 16 + quad * 4 + r) * 256 + ct * 16 + l15] = acc[ct][r] + bct;
  }
}

// ---------------------------------------------------------------------------
extern "C" void kernel_launch(void* const* d_in, const int* in_sizes, int n_in,
                              void* d_out, int out_size, void* d_ws, size_t ws_size,
                              hipStream_t stream)
{
  const float* inp = (const float*)d_in[0];
  const float* wq  = (const float*)d_in[1];
  const float* bq  = (const float*)d_in[2];
  const float* wk  = (const float*)d_in[3];
  const float* bk  = (const float*)d_in[4];
  const float* wv  = (const float*)d_in[5];
  const float* bv  = (const float*)d_in[6];
  const float* wo  = (const float*)d_in[7];
  const float* bo  = (const float*)d_in[8];
  float* out = (float*)d_out;

  // ws (~60 MB): Qh, Kf, Vf (NE f16), Wt (4*65536 f16), Pp (4*NE f16), m/l
  f16* Qh = (f16*)d_ws;
  f16* Kf = Qh + NE;
  f16* Vf = Kf + NE;
  f16* Wt = Vf + NE;
  f16* Pp = Wt + 4 * 65536;
  float* Mp = (float*)(Pp + 4 * NE);
  float* Lp = Mp + 4 * NROWS;

  prep_wt_kernel<<<dim3(256, 4), 256, 0, stream>>>(wq, wk, wv, wo, Wt);

  qkv_mfma_kernel<<<dim3(256, 3), 256, 0, stream>>>(
      inp, Wt, bq, bk, bv, Qh, Kf, Vf);

  attn7_kernel<<<512, 256, 0, stream>>>(Qh, (const char*)Kf, (const char*)Vf,
                                        Pp, Mp, Lp);

  oproj_mfma_kernel<<<256, 256, 0, stream>>>(Pp, Mp, Lp, Wt + 3 * 65536, bo, out);
}

// Round 8
// 243.967 us; speedup vs baseline: 1.4627x; 1.4627x over previous
//
#include <hip/hip_runtime.h>

typedef _Float16 f16;
typedef _Float16 f16x4 __attribute__((ext_vector_type(4)));
typedef _Float16 f16x8 __attribute__((ext_vector_type(8)));
typedef float f32x4  __attribute__((ext_vector_type(4)));

#define MFMAH(a, b, c) __builtin_amdgcn_mfma_f32_16x16x32_f16(a, b, c, 0, 0, 0)

constexpr int D = 256;
constexpr int S = 4096;
constexpr int BATCH = 4;
constexpr int NROWS = BATCH * S;           // 16384
constexpr float SCALE = 0.0625f;           // 1/sqrt(256)
constexpr size_t NE = (size_t)NROWS * D;   // 4.19M elems

// async global->LDS: per-lane src addr, wave-uniform LDS base (+lane*16 by HW)
__device__ __forceinline__ void gll16(const void* g, void* l) {
  __builtin_amdgcn_global_load_lds(
      (const __attribute__((address_space(1))) unsigned int*)g,
      (__attribute__((address_space(3))) unsigned int*)l, 16, 0, 0);
}

// ---------------------------------------------------------------------------
// Prep: Wt[m][n][k] = w_m[k][n] fp16. Write-coalesced (scattered reads L2-ok).
// ---------------------------------------------------------------------------
__global__ __launch_bounds__(256)
void prep_wt_kernel(const float* __restrict__ wq, const float* __restrict__ wk,
                    const float* __restrict__ wv, const float* __restrict__ wo,
                    f16* __restrict__ Wt)
{
  const int m = blockIdx.y;
  const float* w = (m == 0) ? wq : (m == 1) ? wk : (m == 2) ? wv : wo;
  int id = blockIdx.x * 256 + threadIdx.x;    // 0..65535
  int n = id >> 8, k = id & 255;
  Wt[((size_t)m << 16) + n * 256 + k] = (f16)w[k * 256 + n];
}

// ---------------------------------------------------------------------------
// QKV projection via MFMA with LDS-staged B tiles (dbuf, gll16) and
// LDS-transposed coalesced epilogues (r7-validated layouts).
// Q: row-major fp16, scaled by SCALE (natural-log softmax downstream).
// ---------------------------------------------------------------------------
__global__ __launch_bounds__(256)
void qkv_mfma_kernel(const float* __restrict__ in, const f16* __restrict__ Wt,
                     const float* __restrict__ bq, const float* __restrict__ bk,
                     const float* __restrict__ bv,
                     f16* __restrict__ Qh, f16* __restrict__ Kf, f16* __restrict__ Vf)
{
  __shared__ __align__(16) char smem[32768];   // B dbuf (2x16KB); reused by epilogue
  const int m = blockIdx.y;
  const int tid = threadIdx.x, lane = tid & 63, w = tid >> 6;
  const int l15 = lane & 15, quad = lane >> 4;
  const int row0 = blockIdx.x * 64 + w * 16;
  const f16* Wm = Wt + ((size_t)m << 16);
  const float* bias = (m == 0) ? bq : (m == 1) ? bk : bv;

  // ---- A fragments: 16 rows of `in`, fp32 -> fp16 up front
  f16x8 af[8];
  {
    const float* arow = in + (size_t)(row0 + l15) * 768 + m * 256 + quad * 8;
#pragma unroll
    for (int kc = 0; kc < 8; ++kc) {
      float4 a0 = *(const float4*)(arow + kc * 32);
      float4 a1 = *(const float4*)(arow + kc * 32 + 4);
      f16x8 a;
      a[0] = (f16)a0.x; a[1] = (f16)a0.y; a[2] = (f16)a0.z; a[3] = (f16)a0.w;
      a[4] = (f16)a1.x; a[5] = (f16)a1.y; a[6] = (f16)a1.z; a[7] = (f16)a1.w;
      af[kc] = a;
    }
  }

  // ---- stage B(kc) into buffer: wave w stages ct = 4w..4w+3
  auto stageB = [&](int buf, int kc) {
    char* base = smem + buf * 16384;
#pragma unroll
    for (int i = 0; i < 4; ++i) {
      int ct = 4 * w + i;
      gll16(Wm + (ct * 16 + l15) * 256 + kc * 32 + quad * 8,
            base + ct * 1024 + lane * 16);
    }
  };

  f32x4 acc[16];
#pragma unroll
  for (int ct = 0; ct < 16; ++ct) acc[ct] = (f32x4){0.f, 0.f, 0.f, 0.f};

  stageB(0, 0);
  for (int kc = 0; kc < 8; ++kc) {
    __syncthreads();                       // B(kc) staged
    if (kc < 7) stageB((kc + 1) & 1, kc + 1);
    const char* Bb = smem + (kc & 1) * 16384;
#pragma unroll
    for (int ct = 0; ct < 16; ++ct) {
      f16x8 b = *(const f16x8*)(Bb + ct * 1024 + lane * 16);
      acc[ct] = MFMAH(af[kc], b, acc[ct]);
    }
  }
  __syncthreads();                         // B buffers dead; reuse for epilogue

  const int b_ = row0 >> 12;

  if (m == 0) {
    f16* ws = (f16*)(smem + w * 8192);
#pragma unroll
    for (int ct = 0; ct < 16; ++ct) {
      float bct = bias[ct * 16 + l15];
#pragma unroll
      for (int r = 0; r < 4; ++r)
        ws[(quad * 4 + r) * 256 + ct * 16 + l15] = (f16)((acc[ct][r] + bct) * SCALE);
    }
    f16* dst = Qh + (size_t)row0 * 256;
#pragma unroll
    for (int i = 0; i < 8; ++i)
      *(uint4*)(dst + lane * 8 + i * 512) = *(const uint4*)(ws + lane * 8 + i * 512);
  } else if (m == 1) {
    f16* ws = (f16*)(smem + w * 8192);
#pragma unroll
    for (int ct = 0; ct < 16; ++ct) {
      float bct = bias[ct * 16 + l15];
      int base = (ct >> 1) * 512 + ((ct & 1) * 2 + (l15 >> 3)) * 128 + (l15 & 7);
#pragma unroll
      for (int r = 0; r < 4; ++r)
        ws[base + (quad * 4 + r) * 8] = (f16)(acc[ct][r] + bct);
    }
    const int g = (row0 & 4095) >> 4;
    f16* dst = Kf + ((size_t)(b_ * 256 + g)) * 8 * 512;
#pragma unroll
    for (int i = 0; i < 8; ++i)
      *(uint4*)(dst + lane * 8 + i * 512) = *(const uint4*)(ws + lane * 8 + i * 512);
  } else {
    const int t = w & 1;
    f16* ws = (f16*)(smem + (w >> 1) * 16384);
#pragma unroll
    for (int ct = 0; ct < 16; ++ct) {
      float bct = bias[ct * 16 + l15];
      int base = ct * 512 + quad * 128 + l15 * 8 + t * 4;
#pragma unroll
      for (int r = 0; r < 4; ++r)
        ws[base + r] = (f16)(acc[ct][r] + bct);
    }
    __syncthreads();
    const int gv0 = ((blockIdx.x * 64) & 4095) >> 5;
    f16* dst = Vf + ((size_t)(b_ * 128 + gv0)) * 16 * 512;
    const f16* src = (const f16*)smem;
#pragma unroll
    for (int i = 0; i < 8; ++i)
      *(uint4*)(dst + tid * 8 + i * 2048) = *(const uint4*)(src + tid * 8 + i * 2048);
  }
}

// ---------------------------------------------------------------------------
// fp16 MFMA flash attention (exact round-6 attn6: __expf, scalar partial
// stores — measured 123 us). 512 blocks x 256 thr, split-K=4, 32-key tiles.
// ---------------------------------------------------------------------------
__global__ __launch_bounds__(256, 2)
void attn6_kernel(const f16* __restrict__ Qh, const char* __restrict__ Kf,
                  const char* __restrict__ Vf,
                  f16* __restrict__ Pp, float* __restrict__ Mp, float* __restrict__ Lp)
{
  __shared__ __align__(16) char KVs[2][32768];   // [K 16 frags][V 16 frags]

  const int tid = threadIdx.x, lane = tid & 63, w = tid >> 6;
  const int l15 = lane & 15, quad = lane >> 4;

  const int bx    = blockIdx.x;
  const int combo = bx & 15;
  const int b     = combo & 3;
  const int kz    = combo >> 2;
  const int qb    = bx >> 4;                   // 0..31
  const int qrow0 = qb * 128 + w * 32;
  const int grow  = b * 4096 + qrow0;

  f16x8 qf[2][8];
#pragma unroll
  for (int sub = 0; sub < 2; ++sub) {
    const size_t qoff = (size_t)(grow + sub * 16 + l15) * 256 + quad * 8;
#pragma unroll
    for (int kc = 0; kc < 8; ++kc)
      qf[sub][kc] = *(const f16x8*)(Qh + qoff + kc * 32);
  }

  const char* kg[4];
  const char* vg[4];
#pragma unroll
  for (int i = 0; i < 4; ++i) {
    int f = 4 * w + i;
    kg[i] = Kf + (((size_t)(b * 256 + kz * 64 + (f >> 3))) * 8 + (f & 7)) * 1024
               + lane * 16;
    vg[i] = Vf + (((size_t)(b * 128 + kz * 32)) * 16 + f) * 1024 + lane * 16;
  }
  auto stage = [&](int buf) {
    char* base = &KVs[buf][0];
#pragma unroll
    for (int i = 0; i < 4; ++i) { gll16(kg[i], base + (4 * w + i) * 1024); kg[i] += 16384; }
#pragma unroll
    for (int i = 0; i < 4; ++i) { gll16(vg[i], base + 16384 + (4 * w + i) * 1024); vg[i] += 16384; }
  };

  f32x4 o0[16], o1[16];
#pragma unroll
  for (int ct = 0; ct < 16; ++ct) {
    o0[ct] = (f32x4){0.f, 0.f, 0.f, 0.f};
    o1[ct] = (f32x4){0.f, 0.f, 0.f, 0.f};
  }
  float m0 = -3.0e38f, m1 = -3.0e38f, l0 = 0.f, l1 = 0.f;

  stage(0);

  for (int it = 0; it < 32; ++it) {
    __syncthreads();
    if (it < 31) stage((it + 1) & 1);
    const char* Bf = &KVs[it & 1][0];

    f32x4 sA0 = (f32x4){0.f,0.f,0.f,0.f}, sB0 = (f32x4){0.f,0.f,0.f,0.f};
    f32x4 sA1 = (f32x4){0.f,0.f,0.f,0.f}, sB1 = (f32x4){0.f,0.f,0.f,0.f};
#pragma unroll
    for (int kc = 0; kc < 8; ++kc) {
      f16x8 kA = *(const f16x8*)(Bf + kc * 1024 + lane * 16);
      f16x8 kB = *(const f16x8*)(Bf + 8192 + kc * 1024 + lane * 16);
      sA0 = MFMAH(kA, qf[0][kc], sA0);
      sA1 = MFMAH(kA, qf[1][kc], sA1);
      sB0 = MFMAH(kB, qf[0][kc], sB0);
      sB1 = MFMAH(kB, qf[1][kc], sB1);
    }

    float mn0, mn1, al0, al1;
    f16x8 ph0, ph1;
    {
      float t = fmaxf(fmaxf(fmaxf(sA0[0], sA0[1]), fmaxf(sA0[2], sA0[3])),
                      fmaxf(fmaxf(sB0[0], sB0[1]), fmaxf(sB0[2], sB0[3])));
      t = fmaxf(t, __shfl_xor(t, 16));
      t = fmaxf(t, __shfl_xor(t, 32));
      mn0 = fmaxf(m0, t);
      al0 = __expf(m0 - mn0);
      float ps = 0.f;
#pragma unroll
      for (int r = 0; r < 4; ++r) {
        float pa = __expf(sA0[r] - mn0);
        float pb = __expf(sB0[r] - mn0);
        ph0[r] = (f16)pa;  ph0[r + 4] = (f16)pb;
        ps += pa + pb;
      }
      ps += __shfl_xor(ps, 16);
      ps += __shfl_xor(ps, 32);
      l0 = l0 * al0 + ps;
    }
    {
      float t = fmaxf(fmaxf(fmaxf(sA1[0], sA1[1]), fmaxf(sA1[2], sA1[3])),
                      fmaxf(fmaxf(sB1[0], sB1[1]), fmaxf(sB1[2], sB1[3])));
      t = fmaxf(t, __shfl_xor(t, 16));
      t = fmaxf(t, __shfl_xor(t, 32));
      mn1 = fmaxf(m1, t);
      al1 = __expf(m1 - mn1);
      float ps = 0.f;
#pragma unroll
      for (int r = 0; r < 4; ++r) {
        float pa = __expf(sA1[r] - mn1);
        float pb = __expf(sB1[r] - mn1);
        ph1[r] = (f16)pa;  ph1[r + 4] = (f16)pb;
        ps += pa + pb;
      }
      ps += __shfl_xor(ps, 16);
      ps += __shfl_xor(ps, 32);
      l1 = l1 * al1 + ps;
    }

    if (__any(mn0 > m0)) {
      float a0 = __shfl(al0, (quad << 2) + 0);
      float a1 = __shfl(al0, (quad << 2) + 1);
      float a2 = __shfl(al0, (quad << 2) + 2);
      float a3 = __shfl(al0, (quad << 2) + 3);
#pragma unroll
      for (int ct = 0; ct < 16; ++ct) {
        o0[ct][0] *= a0; o0[ct][1] *= a1; o0[ct][2] *= a2; o0[ct][3] *= a3;
      }
    }
    if (__any(mn1 > m1)) {
      float a0 = __shfl(al1, (quad << 2) + 0);
      float a1 = __shfl(al1, (quad << 2) + 1);
      float a2 = __shfl(al1, (quad << 2) + 2);
      float a3 = __shfl(al1, (quad << 2) + 3);
#pragma unroll
      for (int ct = 0; ct < 16; ++ct) {
        o1[ct][0] *= a0; o1[ct][1] *= a1; o1[ct][2] *= a2; o1[ct][3] *= a3;
      }
    }
    m0 = mn0;  m1 = mn1;

#pragma unroll
    for (int ct = 0; ct < 16; ++ct) {
      f16x8 vf = *(const f16x8*)(Bf + 16384 + ct * 1024 + lane * 16);
      o0[ct] = MFMAH(ph0, vf, o0[ct]);
      o1[ct] = MFMAH(ph1, vf, o1[ct]);
    }
  }

  f16* Od = Pp + (size_t)kz * NE;
#pragma unroll
  for (int r = 0; r < 4; ++r) {
    const size_t ro0 = (size_t)(grow + quad * 4 + r) * 256 + l15;
    const size_t ro1 = (size_t)(grow + 16 + quad * 4 + r) * 256 + l15;
#pragma unroll
    for (int ct = 0; ct < 16; ++ct) {
      Od[ro0 + ct * 16] = (f16)o0[ct][r];
      Od[ro1 + ct * 16] = (f16)o1[ct][r];
    }
  }
  if (lane < 16) {
    Mp[kz * NROWS + grow + l15] = m0;
    Lp[kz * NROWS + grow + l15] = l0;
    Mp[kz * NROWS + grow + 16 + l15] = m1;
    Lp[kz * NROWS + grow + 16 + l15] = l1;
  }
}

// ---------------------------------------------------------------------------
// Fused split-K merge + output projection. 512 blocks x 32 rows (2 blocks/CU).
// B tiles LDS-staged (dbuf, gll16). Wave w: rows (w&1)*16, cols (w>>1)*128.
// ---------------------------------------------------------------------------
__global__ __launch_bounds__(256)
void oproj_mfma_kernel(const f16* __restrict__ Pp, const float* __restrict__ Mp,
                       const float* __restrict__ Lp, const f16* __restrict__ Wto,
                       const float* __restrict__ bo, float* __restrict__ out)
{
  __shared__ f16 xs[32][264];                   // 16.5 KB (padded)
  __shared__ __align__(16) char Bs[2][16384];   // 32 KB
  const int tid = threadIdx.x, lane = tid & 63, w = tid >> 6;
  const int l15 = lane & 15, quad = lane >> 4;
  const int rb = blockIdx.x * 32;

  auto stageB = [&](int buf, int kc) {
    char* base = &Bs[buf][0];
#pragma unroll
    for (int i = 0; i < 4; ++i) {
      int ct = 4 * w + i;
      gll16(Wto + (ct * 16 + l15) * 256 + kc * 32 + quad * 8,
            base + ct * 1024 + lane * 16);
    }
  };
  stageB(0, 0);

  // ---- merge prologue: 32 rows x 256 cols, 4-way split-K (natural log)
  const int c4 = (tid & 63) * 4;
  const int rsub = tid >> 6;
#pragma unroll
  for (int e = 0; e < 8; ++e) {
    int rl = e * 4 + rsub;
    int row = rb + rl;
    float m[4], l[4];
#pragma unroll
    for (int z = 0; z < 4; ++z) {
      m[z] = Mp[z * NROWS + row];
      l[z] = Lp[z * NROWS + row];
    }
    float mm = fmaxf(fmaxf(m[0], m[1]), fmaxf(m[2], m[3]));
    float wz[4], denom = 0.f;
#pragma unroll
    for (int z = 0; z < 4; ++z) { wz[z] = __expf(m[z] - mm); denom += wz[z] * l[z]; }
    float inv = 1.0f / denom;
    float s0 = 0.f, s1 = 0.f, s2 = 0.f, s3 = 0.f;
#pragma unroll
    for (int z = 0; z < 4; ++z) {
      f16x4 h = *(const f16x4*)(Pp + (size_t)z * NE + (size_t)row * 256 + c4);
      s0 += wz[z] * (float)h[0];
      s1 += wz[z] * (float)h[1];
      s2 += wz[z] * (float)h[2];
      s3 += wz[z] * (float)h[3];
    }
    f16x4 xv;
    xv[0] = (f16)(s0 * inv); xv[1] = (f16)(s1 * inv);
    xv[2] = (f16)(s2 * inv); xv[3] = (f16)(s3 * inv);
    *(f16x4*)&xs[rl][c4] = xv;
  }

  // ---- GEMM: wave w -> rows (w&1)*16, ct group (w>>1)*8
  const int rw = (w & 1) * 16;
  const int cg = (w >> 1) * 8;
  f32x4 acc[8];
#pragma unroll
  for (int c = 0; c < 8; ++c) acc[c] = (f32x4){0.f, 0.f, 0.f, 0.f};

  for (int kc = 0; kc < 8; ++kc) {
    __syncthreads();                       // B(kc) staged (+ xs ready at kc=0)
    if (kc < 7) stageB((kc + 1) & 1, kc + 1);
    const char* Bb = &Bs[kc & 1][0];
    f16x8 a = *(const f16x8*)&xs[rw + l15][kc * 32 + quad * 8];
#pragma unroll
    for (int c = 0; c < 8; ++c) {
      f16x8 b = *(const f16x8*)(Bb + (cg + c) * 1024 + lane * 16);
      acc[c] = MFMAH(a, b, acc[c]);
    }
  }

#pragma unroll
  for (int c = 0; c < 8; ++c) {
    int col = (cg + c) * 16 + l15;
    float bct = bo[col];
#pragma unroll
    for (int r = 0; r < 4; ++r)
      out[(size_t)(rb + rw + quad * 4 + r) * 256 + col] = acc[c][r] + bct;
  }
}

// ---------------------------------------------------------------------------
extern "C" void kernel_launch(void* const* d_in, const int* in_sizes, int n_in,
                              void* d_out, int out_size, void* d_ws, size_t ws_size,
                              hipStream_t stream)
{
  const float* inp = (const float*)d_in[0];
  const float* wq  = (const float*)d_in[1];
  const float* bq  = (const float*)d_in[2];
  const float* wk  = (const float*)d_in[3];
  const float* bk  = (const float*)d_in[4];
  const float* wv  = (const float*)d_in[5];
  const float* bv  = (const float*)d_in[6];
  const float* wo  = (const float*)d_in[7];
  const float* bo  = (const float*)d_in[8];
  float* out = (float*)d_out;

  // ws (~60 MB): Qh, Kf, Vf (NE f16), Wt (4*65536 f16), Pp (4*NE f16), m/l
  f16* Qh = (f16*)d_ws;
  f16* Kf = Qh + NE;
  f16* Vf = Kf + NE;
  f16* Wt = Vf + NE;
  f16* Pp = Wt + 4 * 65536;
  float* Mp = (float*)(Pp + 4 * NE);
  float* Lp = Mp + 4 * NROWS;

  prep_wt_kernel<<<dim3(256, 4), 256, 0, stream>>>(wq, wk, wv, wo, Wt);

  qkv_mfma_kernel<<<dim3(256, 3), 256, 0, stream>>>(
      inp, Wt, bq, bk, bv, Qh, Kf, Vf);

  attn6_kernel<<<512, 256, 0, stream>>>(Qh, (const char*)Kf, (const char*)Vf,
                                        Pp, Mp, Lp);

  oproj_mfma_kernel<<<512, 256, 0, stream>>>(Pp, Mp, Lp, Wt + 3 * 65536, bo, out);
}